// Round 17
// baseline (76.933 us; speedup 1.0000x reference)
//
#include <hip/hip_runtime.h>

#define NPOS 4096      // H*W
#define NCH  256       // channels
#define HD   32        // head dim
#define KB   64        // keys per attention step

// fragment-tiled layout: element (row o, col c) of a [R][256] bf16 matrix at
// ushort offset TOFF(o,c); a wave's (o-tile, kc) fragment = contiguous 1KB.
#define TOFF(o, c) (((((o) >> 4) * 8 + ((c) >> 5)) * 64 + \
                     ((((c) >> 3) & 3) * 16) + ((o) & 15)) * 8 + ((c) & 7))

typedef float f32x4  __attribute__((ext_vector_type(4)));
typedef float f32x16 __attribute__((ext_vector_type(16)));
typedef short s16x8  __attribute__((ext_vector_type(8)));
typedef uint  u32x2  __attribute__((ext_vector_type(2)));
typedef uint  u32x4  __attribute__((ext_vector_type(4)));
typedef int   i32x2  __attribute__((ext_vector_type(2)));

static __device__ __forceinline__ s16x8 load8(const ushort* p) {
    return *(const s16x8*)p;
}
static __device__ __forceinline__ ushort bfbits(float x) {
    __bf16 b = (__bf16)x;
    return __builtin_bit_cast(unsigned short, b);
}
static __device__ __forceinline__ float bfval(ushort u) {
    uint x = (uint)u << 16;
    return __builtin_bit_cast(float, x);
}
static __device__ __forceinline__ uint pk2(float a, float b) {
    return (uint)bfbits(a) | ((uint)bfbits(b) << 16);
}
// permlane32_swap: per lane, results {a,b} hold {own-half, partner-half}
static __device__ __forceinline__ void plswap(uint& a, uint& b) {
    i32x2 r = __builtin_amdgcn_permlane32_swap((int)a, (int)b, false, false);
    a = (uint)r[0];
    b = (uint)r[1];
}

// ---------------- W conversion (tiled) ----------------
__global__ __launch_bounds__(256) void convert_w_kernel(
    const float* __restrict__ Wq, const float* __restrict__ Wk,
    const float* __restrict__ Wv, const float* __restrict__ Wp,
    ushort* __restrict__ wsp, float qscale)
{
    const int m = blockIdx.y;
    const float* src = m == 0 ? Wq : m == 1 ? Wk : m == 2 ? Wv : Wp;
    const float sc = m == 0 ? qscale : 1.f;
    const int idx = (blockIdx.x * 256 + threadIdx.x) * 4;
    const int o = idx >> 8, c0 = idx & 255;
    f32x4 w = *(const f32x4*)(src + idx);
    w *= sc;
    ushort h[4], l[4];
#pragma unroll
    for (int i = 0; i < 4; ++i) {
        h[i] = bfbits(w[i]);
        l[i] = bfbits(w[i] - bfval(h[i]));
    }
    ushort* H = wsp + m * 2 * 65536;
    const int off = TOFF(o, c0);
    *(u32x2*)(H + off)         = (u32x2){(uint)h[0] | ((uint)h[1] << 16),
                                         (uint)h[2] | ((uint)h[3] << 16)};
    *(u32x2*)(H + 65536 + off) = (u32x2){(uint)l[0] | ((uint)l[1] << 16),
                                         (uint)l[2] | ((uint)l[3] << 16)};
}

// ------- fused x-convert + QKV projection (bf16x3 MFMA, LDS B) -------
__global__ __launch_bounds__(256) void fused_qkv_kernel(
    const float* __restrict__ x1, const float* __restrict__ x2,
    const ushort* __restrict__ wsp,
    ushort* __restrict__ qt, ushort* __restrict__ kt, ushort* __restrict__ vt)
{
    __shared__ __align__(16) ushort lds[32768];  // x1h,x1l,x2h,x2l @ 8192 each
    const int tid   = threadIdx.x;
    const int n0    = blockIdx.x * 32;
    const int obase = blockIdx.y * 128;

    // --- phase 1: convert x slice -> LDS tiled hi/lo ---
    {
        const int ln = tid & 7;        // n group (ln*4)
        const int cr = tid >> 3;       // 0..31
#pragma unroll
        for (int pass = 0; pass < 16; ++pass) {
            const int c = (pass & 7) * 32 + cr;
            const float* X = (pass < 8) ? x1 : x2;
            const int rbase = (pass < 8) ? 0 : 16384;
            const f32x4 v = *(const f32x4*)(X + (size_t)c * NPOS + n0 + ln * 4);
#pragma unroll
            for (int i = 0; i < 4; ++i) {
                const int nl = ln * 4 + i;
                const ushort hb = bfbits(v[i]);
                const ushort lb = bfbits(v[i] - bfval(hb));
                const int idx = (((nl >> 4) * 8 + (c >> 5)) * 64 +
                                 (((c >> 3) & 3) * 16) + (nl & 15)) * 8 + (c & 7);
                lds[rbase + idx]        = hb;
                lds[rbase + 8192 + idx] = lb;
            }
        }
    }
    __syncthreads();

    // --- phase 2: GEMMs ---
    const int wid = tid >> 6, lane = tid & 63;
    const int lq = lane & 15, grp = lane >> 4;

    f32x4 acc[3][2][2];
#pragma unroll
    for (int m = 0; m < 3; ++m)
#pragma unroll
        for (int ot = 0; ot < 2; ++ot)
#pragma unroll
            for (int nt = 0; nt < 2; ++nt)
                acc[m][ot][nt] = (f32x4){0.f, 0.f, 0.f, 0.f};

#pragma unroll
    for (int kc = 0; kc < 8; ++kc) {
#pragma unroll
        for (int m = 0; m < 3; ++m) {
            const ushort* W = wsp + m * 131072;
            const int bb = (m == 0) ? 0 : 16384;
#pragma unroll
            for (int ot = 0; ot < 2; ++ot) {
                const int To = (obase + (wid * 2 + ot) * 16) >> 4;
                const s16x8 ah = load8(W + ((To * 8 + kc) * 64 + lane) * 8);
                const s16x8 al = load8(W + 65536 + ((To * 8 + kc) * 64 + lane) * 8);
#pragma unroll
                for (int nt = 0; nt < 2; ++nt) {
                    const s16x8 bh = *(const s16x8*)(lds + bb +
                                        ((nt * 8 + kc) * 64 + lane) * 8);
                    const s16x8 bl = *(const s16x8*)(lds + bb + 8192 +
                                        ((nt * 8 + kc) * 64 + lane) * 8);
                    acc[m][ot][nt] = __builtin_amdgcn_mfma_f32_16x16x32_bf16(
                        ah, bh, acc[m][ot][nt], 0, 0, 0);
                    acc[m][ot][nt] = __builtin_amdgcn_mfma_f32_16x16x32_bf16(
                        ah, bl, acc[m][ot][nt], 0, 0, 0);
                    acc[m][ot][nt] = __builtin_amdgcn_mfma_f32_16x16x32_bf16(
                        al, bh, acc[m][ot][nt], 0, 0, 0);
                }
            }
        }
    }

    // --- epilogue ---
#pragma unroll
    for (int m = 0; m < 3; ++m)
#pragma unroll
        for (int ot = 0; ot < 2; ++ot) {
            const int o0 = obase + (wid * 2 + ot) * 16;
            if (m < 2) {
                ushort* Y = m ? kt : qt;
                const int head = o0 >> 5, d0 = (o0 & 31) + grp * 4;
#pragma unroll
                for (int nt = 0; nt < 2; ++nt) {
                    const int n = n0 + nt * 16 + lq;
                    *(u32x2*)(Y + head * (NPOS * HD) + n * HD + d0) =
                        (u32x2){pk2(acc[m][ot][nt][0], acc[m][ot][nt][1]),
                                pk2(acc[m][ot][nt][2], acc[m][ot][nt][3])};
                }
            } else {
#pragma unroll
                for (int nt = 0; nt < 2; ++nt) {
                    const int n = n0 + nt * 16 + lq;
#pragma unroll
                    for (int r = 0; r < 4; ++r)
                        vt[(o0 + grp * 4 + r) * NPOS + n] =
                            bfbits(acc[2][ot][nt][r]);
                }
            }
        }
}

// ---- MFMA flash attention: 32x32, no max, KB=64, split-K=NS ----
// grid NS*256: s = bid>>8, h = bid&7, qblk = (bid&255)>>3.
// LDS 19456B -> up to 8 blocks/CU; no launch-bounds clamp (R14 lesson).
template <int NS>
__global__ __launch_bounds__(256) void attn_mfma_kernel(
    const ushort* __restrict__ Qt,   // [8][4096][32] bf16, pre-scaled s*log2e
    const ushort* __restrict__ Kt,   // [8][4096][32] bf16
    const ushort* __restrict__ Vt,   // [8][32][4096] bf16
    ushort* __restrict__ Opb,        // [NS][4096][256] bf16 unnormalized
    float* __restrict__ Ml)          // [NS][8][4096] f32 (l)
{
    constexpr int SPLIT = NPOS / NS;
    constexpr int NSTEP = SPLIT / KB;
    __shared__ __align__(16) ushort lds[9728];   // K0@0 K1@2560 V0@5120 V1@7424
    const int bid  = blockIdx.x;
    const int s    = bid >> 8;
    const int h    = bid & 7;
    const int qblk = (bid & 255) >> 3;   // 0..31
    const int tid  = threadIdx.x;
    const int wid  = tid >> 6;
    const int lane = tid & 63;
    const int l31  = lane & 31;
    const int hi   = lane >> 5;
    const int q0   = qblk * 128 + wid * 32;
    const int k0   = s * SPLIT;
    const int hq   = h * (NPOS * HD);

    s16x8 qf[2];
#pragma unroll
    for (int kh = 0; kh < 2; ++kh)
        qf[kh] = load8(Qt + hq + (q0 + l31) * HD + kh * 16 + hi * 8);

    const int kr0 = tid >> 2, kc0 = tid & 3;
    const ushort* kS = Kt + hq + kr0 * HD + kc0 * 8;
    const int kdst = kr0 * 40 + (((kc0 ^ (kr0 >> 3)) & 3) << 3);

    const int vr0 = tid >> 3, vc0 = tid & 7;
    const ushort* vS = Vt + h * (HD * NPOS) + vr0 * NPOS + vc0 * 8;
    const int vdst = vr0 * 72 + (((vc0 ^ (vr0 >> 3)) & 7) << 3);

    const int kx = l31 >> 3;

    f32x16 oacc = {};
    float lacc = 0.f;

    // prologue: tile0 -> buf0; prefetch tile1 into regs
    *(s16x8*)(lds + kdst)        = load8(kS + (size_t)k0 * HD);
    *(s16x8*)(lds + 5120 + vdst) = load8(vS + k0);
    const int m1 = (NSTEP > 1) ? k0 + KB : k0;
    s16x8 kra = load8(kS + (size_t)m1 * HD);
    s16x8 vra = load8(vS + m1);
    __syncthreads();

    for (int step = 0; step < NSTEP; ++step) {
        const int cur = step & 1;
        ushort* const Kb = lds + cur * 2560;
        ushort* const Vb = lds + 5120 + cur * 2304;

        // write prefetched tile (step+1) into the other buffer
        {
            ushort* const Kn = lds + (cur ^ 1) * 2560;
            ushort* const Vn = lds + 5120 + (cur ^ 1) * 2304;
            *(s16x8*)(Kn + kdst) = kra;
            *(s16x8*)(Vn + vdst) = vra;
        }
        // issue loads for tile step+2
        const int mn = (step + 2 < NSTEP) ? k0 + (step + 2) * KB : k0;
        kra = load8(kS + (size_t)mn * HD);
        vra = load8(vS + mn);

#pragma unroll
        for (int t = 0; t < 2; ++t) {
            const int krow = (t * 32 + l31) * 40;
            const s16x8 kfa = *(const s16x8*)(Kb + krow + (((hi ^ kx) & 3) << 3));
            const s16x8 kfb = *(const s16x8*)(Kb + krow + ((((2 + hi) ^ kx) & 3) << 3));
            f32x16 st = {};
            __builtin_amdgcn_s_setprio(1);
            st = __builtin_amdgcn_mfma_f32_32x32x16_bf16(kfa, qf[0], st, 0, 0, 0);
            st = __builtin_amdgcn_mfma_f32_32x32x16_bf16(kfb, qf[1], st, 0, 0, 0);
            __builtin_amdgcn_s_setprio(0);

            const s16x8 vf0 = *(const s16x8*)(Vb + l31 * 72 +
                                              ((((t * 4 + hi) ^ kx) & 7) << 3));
            const s16x8 vf1 = *(const s16x8*)(Vb + l31 * 72 +
                                              ((((t * 4 + 2 + hi) ^ kx) & 7) << 3));

            uint w[4], w2[4];
            float ls = 0.f;
#pragma unroll
            for (int g = 0; g < 4; ++g) {
                const float p0 = __builtin_amdgcn_exp2f(st[4 * g + 0]);
                const float p1 = __builtin_amdgcn_exp2f(st[4 * g + 1]);
                const float p2 = __builtin_amdgcn_exp2f(st[4 * g + 2]);
                const float p3 = __builtin_amdgcn_exp2f(st[4 * g + 3]);
                ls += (p0 + p1) + (p2 + p3);
                w[g]  = pk2(p0, p1);
                w2[g] = pk2(p2, p3);
            }
            lacc += ls;
            uint a0 = w[0],  c0 = w[1];  plswap(a0, c0);
            uint a1 = w2[0], c1 = w2[1]; plswap(a1, c1);
            const s16x8 pfA = __builtin_bit_cast(s16x8, (u32x4){a0, a1, c0, c1});
            uint b0 = w[2],  d0 = w[3];  plswap(b0, d0);
            uint b1 = w2[2], d1 = w2[3]; plswap(b1, d1);
            const s16x8 pfB = __builtin_bit_cast(s16x8, (u32x4){b0, b1, d0, d1});

            __builtin_amdgcn_s_setprio(1);
            oacc = __builtin_amdgcn_mfma_f32_32x32x16_bf16(vf0, pfA, oacc, 0, 0, 0);
            oacc = __builtin_amdgcn_mfma_f32_32x32x16_bf16(vf1, pfB, oacc, 0, 0, 0);
            __builtin_amdgcn_s_setprio(0);
        }

        __syncthreads();
    }

    // l: lacc covers my 16 rows; partner lane (l^32) has the other 16.
    {
        uint a = __builtin_bit_cast(uint, lacc), b = a;
        plswap(a, b);
        lacc = __builtin_bit_cast(float, a) + __builtin_bit_cast(float, b);
    }

    const int n = q0 + l31;
    ushort* Ops = Opb + (size_t)s * (NPOS * NCH) + n * NCH + h * HD;
#pragma unroll
    for (int g = 0; g < 4; ++g) {
        *(u32x2*)(Ops + g * 8 + hi * 4) =
            (u32x2){pk2(oacc[4 * g + 0], oacc[4 * g + 1]),
                    pk2(oacc[4 * g + 2], oacc[4 * g + 3])};
    }
    if (lane < 32)
        Ml[(s * 8 + h) * NPOS + n] = lacc;
}

// ------- fused split-K combine + output projection -------
template <int NS>
__global__ __launch_bounds__(256) void fused_out_kernel(
    const ushort* __restrict__ Opb, const float* __restrict__ Ml,
    const ushort* __restrict__ Wh, const ushort* __restrict__ Wl,
    const float* __restrict__ bias, float* __restrict__ Y)
{
    __shared__ __align__(16) ushort lds[8192];   // hi @0, lo @4096 (ushorts)
    const int tid = threadIdx.x;
    const int n0  = blockIdx.x * 16;

    // --- phase 1: combine -> LDS tiled hi/lo ---
    {
        const int nl = tid >> 4;              // 0..15
        const int c0 = (tid & 15) * 16;
        const int n  = n0 + nl;
        const int h  = c0 >> 5;
        float l = 0.f;
#pragma unroll
        for (int s = 0; s < NS; ++s)
            l += Ml[(s * 8 + h) * NPOS + n];
        const float inv = 1.f / l;

        float f[16];
#pragma unroll
        for (int i = 0; i < 16; ++i) f[i] = 0.f;
#pragma unroll
        for (int s = 0; s < NS; ++s) {
            const s16x8 r0 = load8(Opb + (size_t)s * (NPOS * NCH) + n * NCH + c0);
            const s16x8 r1 = load8(Opb + (size_t)s * (NPOS * NCH) + n * NCH + c0 + 8);
#pragma unroll
            for (int i = 0; i < 8; ++i) {
                f[i]     += bfval((ushort)r0[i]);
                f[i + 8] += bfval((ushort)r1[i]);
            }
        }
#pragma unroll
        for (int i = 0; i < 16; ++i) {
            const int c = c0 + i;
            const float v = f[i] * inv;
            const ushort hb = bfbits(v);
            const ushort lb = bfbits(v - bfval(hb));
            const int idx = ((c >> 5) * 64 + (((c >> 3) & 3) * 16) + nl) * 8 + (c & 7);
            lds[idx]        = hb;
            lds[4096 + idx] = lb;
        }
    }
    __syncthreads();

    // --- phase 2: C = Wp @ F + bias ---
    const int wid = tid >> 6, lane = tid & 63;
    const int lq = lane & 15, grp = lane >> 4;

    f32x4 acc[4];
#pragma unroll
    for (int ot = 0; ot < 4; ++ot) acc[ot] = (f32x4){0.f, 0.f, 0.f, 0.f};

#pragma unroll
    for (int kc = 0; kc < 8; ++kc) {
        const s16x8 bh = *(const s16x8*)(lds + (kc * 64 + lane) * 8);
        const s16x8 bl = *(const s16x8*)(lds + 4096 + (kc * 64 + lane) * 8);
#pragma unroll
        for (int ot = 0; ot < 4; ++ot) {
            const int To = wid * 4 + ot;
            const s16x8 ah = load8(Wh + ((To * 8 + kc) * 64 + lane) * 8);
            const s16x8 al = load8(Wl + ((To * 8 + kc) * 64 + lane) * 8);
            acc[ot] = __builtin_amdgcn_mfma_f32_16x16x32_bf16(ah, bh, acc[ot], 0, 0, 0);
            acc[ot] = __builtin_amdgcn_mfma_f32_16x16x32_bf16(ah, bl, acc[ot], 0, 0, 0);
            acc[ot] = __builtin_amdgcn_mfma_f32_16x16x32_bf16(al, bh, acc[ot], 0, 0, 0);
        }
    }

#pragma unroll
    for (int ot = 0; ot < 4; ++ot) {
        const int o0 = (wid * 4 + ot) * 16;
        const f32x4 b4 = *(const f32x4*)(bias + o0 + grp * 4);
#pragma unroll
        for (int r = 0; r < 4; ++r)
            Y[(o0 + grp * 4 + r) * NPOS + n0 + lq] = acc[ot][r] + b4[r];
    }
}

extern "C" void kernel_launch(void* const* d_in, const int* in_sizes, int n_in,
                              void* d_out, int out_size, void* d_ws, size_t ws_size,
                              hipStream_t stream) {
    const float* x1 = (const float*)d_in[0];
    const float* x2 = (const float*)d_in[1];
    const float* Wq = (const float*)d_in[2];
    const float* Wk = (const float*)d_in[3];
    const float* Wv = (const float*)d_in[4];
    const float* Wp = (const float*)d_in[5];
    const float* bp = (const float*)d_in[6];
    float* out = (float*)d_out;

    const size_t MB = 1u << 20;
    char* wsc = (char*)d_ws;
    const float qscale = (float)(0.17677669529663687 * 1.4426950408889634);

    if (ws_size >= 25 * MB) {
        // NSPLIT=8 layout: Opb 16MB @0, qt@16, kt@18, vt@20, wsp@22, Ml@23.25
        ushort* Opb = (ushort*)(wsc + 0 * MB);
        ushort* qt  = (ushort*)(wsc + 16 * MB);
        ushort* kt  = (ushort*)(wsc + 18 * MB);
        ushort* vt  = (ushort*)(wsc + 20 * MB);
        ushort* wsp = (ushort*)(wsc + 22 * MB);
        float*  Ml  = (float*)(wsc + 23 * MB + 256 * 1024);

        convert_w_kernel<<<dim3(64, 4), 256, 0, stream>>>(
            Wq, Wk, Wv, Wp, wsp, qscale);
        fused_qkv_kernel<<<dim3(128, 2), 256, 0, stream>>>(
            x1, x2, wsp, qt, kt, vt);
        attn_mfma_kernel<8><<<2048, 256, 0, stream>>>(qt, kt, vt, Opb, Ml);
        fused_out_kernel<8><<<256, 256, 0, stream>>>(
            Opb, Ml, wsp + 393216, wsp + 458752, bp, out);
    } else {
        // NSPLIT=4 layout (proven): Opb 8MB @0, qt@8, kt@10, vt@12, wsp@14, Ml@15
        ushort* Opb = (ushort*)(wsc + 0 * MB);
        ushort* qt  = (ushort*)(wsc + 8 * MB);
        ushort* kt  = (ushort*)(wsc + 10 * MB);
        ushort* vt  = (ushort*)(wsc + 12 * MB);
        ushort* wsp = (ushort*)(wsc + 14 * MB);
        float*  Ml  = (float*)(wsc + 15 * MB);

        convert_w_kernel<<<dim3(64, 4), 256, 0, stream>>>(
            Wq, Wk, Wv, Wp, wsp, qscale);
        fused_qkv_kernel<<<dim3(128, 2), 256, 0, stream>>>(
            x1, x2, wsp, qt, kt, vt);
        attn_mfma_kernel<4><<<1024, 256, 0, stream>>>(qt, kt, vt, Opb, Ml);
        fused_out_kernel<4><<<256, 256, 0, stream>>>(
            Opb, Ml, wsp + 393216, wsp + 458752, bp, out);
    }
}

// Round 18
// 76.630 us; speedup vs baseline: 1.0040x; 1.0040x over previous
//
#include <hip/hip_runtime.h>

#define NPOS 4096      // H*W
#define NCH  256       // channels
#define HD   32        // head dim
#define KB   64        // keys per attention step

// fragment-tiled layout: element (row o, col c) of a [R][256] bf16 matrix at
// ushort offset TOFF(o,c); a wave's (o-tile, kc) fragment = contiguous 1KB.
#define TOFF(o, c) (((((o) >> 4) * 8 + ((c) >> 5)) * 64 + \
                     ((((c) >> 3) & 3) * 16) + ((o) & 15)) * 8 + ((c) & 7))

typedef float f32x4  __attribute__((ext_vector_type(4)));
typedef float f32x16 __attribute__((ext_vector_type(16)));
typedef short s16x8  __attribute__((ext_vector_type(8)));
typedef uint  u32x2  __attribute__((ext_vector_type(2)));
typedef uint  u32x4  __attribute__((ext_vector_type(4)));
typedef int   i32x2  __attribute__((ext_vector_type(2)));

static __device__ __forceinline__ s16x8 load8(const ushort* p) {
    return *(const s16x8*)p;
}
static __device__ __forceinline__ ushort bfbits(float x) {
    __bf16 b = (__bf16)x;
    return __builtin_bit_cast(unsigned short, b);
}
static __device__ __forceinline__ float bfval(ushort u) {
    uint x = (uint)u << 16;
    return __builtin_bit_cast(float, x);
}
static __device__ __forceinline__ uint pk2(float a, float b) {
    return (uint)bfbits(a) | ((uint)bfbits(b) << 16);
}
// permlane32_swap: per lane, results {a,b} hold {own-half, partner-half}
static __device__ __forceinline__ void plswap(uint& a, uint& b) {
    i32x2 r = __builtin_amdgcn_permlane32_swap((int)a, (int)b, false, false);
    a = (uint)r[0];
    b = (uint)r[1];
}

// ---------------- W conversion (tiled) ----------------
__global__ __launch_bounds__(256) void convert_w_kernel(
    const float* __restrict__ Wq, const float* __restrict__ Wk,
    const float* __restrict__ Wv, const float* __restrict__ Wp,
    ushort* __restrict__ wsp, float qscale)
{
    const int m = blockIdx.y;
    const float* src = m == 0 ? Wq : m == 1 ? Wk : m == 2 ? Wv : Wp;
    const float sc = m == 0 ? qscale : 1.f;
    const int idx = (blockIdx.x * 256 + threadIdx.x) * 4;
    const int o = idx >> 8, c0 = idx & 255;
    f32x4 w = *(const f32x4*)(src + idx);
    w *= sc;
    ushort h[4], l[4];
#pragma unroll
    for (int i = 0; i < 4; ++i) {
        h[i] = bfbits(w[i]);
        l[i] = bfbits(w[i] - bfval(h[i]));
    }
    ushort* H = wsp + m * 2 * 65536;
    const int off = TOFF(o, c0);
    *(u32x2*)(H + off)         = (u32x2){(uint)h[0] | ((uint)h[1] << 16),
                                         (uint)h[2] | ((uint)h[3] << 16)};
    *(u32x2*)(H + 65536 + off) = (u32x2){(uint)l[0] | ((uint)l[1] << 16),
                                         (uint)l[2] | ((uint)l[3] << 16)};
}

// ------- fused x-convert + QKV projection (bf16x3 MFMA, LDS B) -------
__global__ __launch_bounds__(256) void fused_qkv_kernel(
    const float* __restrict__ x1, const float* __restrict__ x2,
    const ushort* __restrict__ wsp,
    ushort* __restrict__ qt, ushort* __restrict__ kt, ushort* __restrict__ vt)
{
    __shared__ __align__(16) ushort lds[32768];  // x1h,x1l,x2h,x2l @ 8192 each
    const int tid   = threadIdx.x;
    const int n0    = blockIdx.x * 32;
    const int obase = blockIdx.y * 128;

    // --- phase 1: convert x slice -> LDS tiled hi/lo ---
    {
        const int ln = tid & 7;        // n group (ln*4)
        const int cr = tid >> 3;       // 0..31
#pragma unroll
        for (int pass = 0; pass < 16; ++pass) {
            const int c = (pass & 7) * 32 + cr;
            const float* X = (pass < 8) ? x1 : x2;
            const int rbase = (pass < 8) ? 0 : 16384;
            const f32x4 v = *(const f32x4*)(X + (size_t)c * NPOS + n0 + ln * 4);
#pragma unroll
            for (int i = 0; i < 4; ++i) {
                const int nl = ln * 4 + i;
                const ushort hb = bfbits(v[i]);
                const ushort lb = bfbits(v[i] - bfval(hb));
                const int idx = (((nl >> 4) * 8 + (c >> 5)) * 64 +
                                 (((c >> 3) & 3) * 16) + (nl & 15)) * 8 + (c & 7);
                lds[rbase + idx]        = hb;
                lds[rbase + 8192 + idx] = lb;
            }
        }
    }
    __syncthreads();

    // --- phase 2: GEMMs ---
    const int wid = tid >> 6, lane = tid & 63;
    const int lq = lane & 15, grp = lane >> 4;

    f32x4 acc[3][2][2];
#pragma unroll
    for (int m = 0; m < 3; ++m)
#pragma unroll
        for (int ot = 0; ot < 2; ++ot)
#pragma unroll
            for (int nt = 0; nt < 2; ++nt)
                acc[m][ot][nt] = (f32x4){0.f, 0.f, 0.f, 0.f};

#pragma unroll
    for (int kc = 0; kc < 8; ++kc) {
#pragma unroll
        for (int m = 0; m < 3; ++m) {
            const ushort* W = wsp + m * 131072;
            const int bb = (m == 0) ? 0 : 16384;
#pragma unroll
            for (int ot = 0; ot < 2; ++ot) {
                const int To = (obase + (wid * 2 + ot) * 16) >> 4;
                const s16x8 ah = load8(W + ((To * 8 + kc) * 64 + lane) * 8);
                const s16x8 al = load8(W + 65536 + ((To * 8 + kc) * 64 + lane) * 8);
#pragma unroll
                for (int nt = 0; nt < 2; ++nt) {
                    const s16x8 bh = *(const s16x8*)(lds + bb +
                                        ((nt * 8 + kc) * 64 + lane) * 8);
                    const s16x8 bl = *(const s16x8*)(lds + bb + 8192 +
                                        ((nt * 8 + kc) * 64 + lane) * 8);
                    acc[m][ot][nt] = __builtin_amdgcn_mfma_f32_16x16x32_bf16(
                        ah, bh, acc[m][ot][nt], 0, 0, 0);
                    acc[m][ot][nt] = __builtin_amdgcn_mfma_f32_16x16x32_bf16(
                        ah, bl, acc[m][ot][nt], 0, 0, 0);
                    acc[m][ot][nt] = __builtin_amdgcn_mfma_f32_16x16x32_bf16(
                        al, bh, acc[m][ot][nt], 0, 0, 0);
                }
            }
        }
    }

    // --- epilogue ---
#pragma unroll
    for (int m = 0; m < 3; ++m)
#pragma unroll
        for (int ot = 0; ot < 2; ++ot) {
            const int o0 = obase + (wid * 2 + ot) * 16;
            if (m < 2) {
                ushort* Y = m ? kt : qt;
                const int head = o0 >> 5, d0 = (o0 & 31) + grp * 4;
#pragma unroll
                for (int nt = 0; nt < 2; ++nt) {
                    const int n = n0 + nt * 16 + lq;
                    *(u32x2*)(Y + head * (NPOS * HD) + n * HD + d0) =
                        (u32x2){pk2(acc[m][ot][nt][0], acc[m][ot][nt][1]),
                                pk2(acc[m][ot][nt][2], acc[m][ot][nt][3])};
                }
            } else {
#pragma unroll
                for (int nt = 0; nt < 2; ++nt) {
                    const int n = n0 + nt * 16 + lq;
#pragma unroll
                    for (int r = 0; r < 4; ++r)
                        vt[(o0 + grp * 4 + r) * NPOS + n] =
                            bfbits(acc[2][ot][nt][r]);
                }
            }
        }
}

// ---- MFMA flash attention: 32x32, no max, KB=64, 64 queries/wave ----
// grid NS*128: s = bid>>7, h = (bid>>4)&7, qblk = bid&15. Block covers
// 256 q (4 waves x 2 q-tiles). K/V frags read once per two q-tiles.
template <int NS>
__global__ __launch_bounds__(256) void attn_mfma_kernel(
    const ushort* __restrict__ Qt,   // [8][4096][32] bf16, pre-scaled s*log2e
    const ushort* __restrict__ Kt,   // [8][4096][32] bf16
    const ushort* __restrict__ Vt,   // [8][32][4096] bf16
    ushort* __restrict__ Opb,        // [NS][4096][256] bf16 unnormalized
    float* __restrict__ Ml)          // [NS][8][4096] f32 (l)
{
    constexpr int SPLIT = NPOS / NS;
    constexpr int NSTEP = SPLIT / KB;
    __shared__ __align__(16) ushort lds[9728];   // K0@0 K1@2560 V0@5120 V1@7424
    const int bid  = blockIdx.x;
    const int s    = bid >> 7;
    const int h    = (bid >> 4) & 7;
    const int qblk = bid & 15;           // 0..15
    const int tid  = threadIdx.x;
    const int wid  = tid >> 6;
    const int lane = tid & 63;
    const int l31  = lane & 31;
    const int hi   = lane >> 5;
    const int q0   = qblk * 256 + wid * 64;
    const int k0   = s * SPLIT;
    const int hq   = h * (NPOS * HD);

    s16x8 qf[2][2];
#pragma unroll
    for (int qt = 0; qt < 2; ++qt)
#pragma unroll
        for (int kh = 0; kh < 2; ++kh)
            qf[qt][kh] = load8(Qt + hq + (q0 + qt * 32 + l31) * HD + kh * 16 + hi * 8);

    const int kr0 = tid >> 2, kc0 = tid & 3;
    const ushort* kS = Kt + hq + kr0 * HD + kc0 * 8;
    const int kdst = kr0 * 40 + (((kc0 ^ (kr0 >> 3)) & 3) << 3);

    const int vr0 = tid >> 3, vc0 = tid & 7;
    const ushort* vS = Vt + h * (HD * NPOS) + vr0 * NPOS + vc0 * 8;
    const int vdst = vr0 * 72 + (((vc0 ^ (vr0 >> 3)) & 7) << 3);

    const int kx = l31 >> 3;

    f32x16 oaccA = {}, oaccB = {};
    float laccA = 0.f, laccB = 0.f;

    // prologue: tile0 -> buf0; prefetch tile1 into regs
    *(s16x8*)(lds + kdst)        = load8(kS + (size_t)k0 * HD);
    *(s16x8*)(lds + 5120 + vdst) = load8(vS + k0);
    const int m1 = (NSTEP > 1) ? k0 + KB : k0;
    s16x8 kra = load8(kS + (size_t)m1 * HD);
    s16x8 vra = load8(vS + m1);
    __syncthreads();

    for (int step = 0; step < NSTEP; ++step) {
        const int cur = step & 1;
        ushort* const Kb = lds + cur * 2560;
        ushort* const Vb = lds + 5120 + cur * 2304;

        // write prefetched tile (step+1) into the other buffer
        {
            ushort* const Kn = lds + (cur ^ 1) * 2560;
            ushort* const Vn = lds + 5120 + (cur ^ 1) * 2304;
            *(s16x8*)(Kn + kdst) = kra;
            *(s16x8*)(Vn + vdst) = vra;
        }
        // issue loads for tile step+2
        const int mn = (step + 2 < NSTEP) ? k0 + (step + 2) * KB : k0;
        kra = load8(kS + (size_t)mn * HD);
        vra = load8(vS + mn);

#pragma unroll
        for (int t = 0; t < 2; ++t) {
            const int krow = (t * 32 + l31) * 40;
            const s16x8 kfa = *(const s16x8*)(Kb + krow + (((hi ^ kx) & 3) << 3));
            const s16x8 kfb = *(const s16x8*)(Kb + krow + ((((2 + hi) ^ kx) & 3) << 3));
            const s16x8 vf0 = *(const s16x8*)(Vb + l31 * 72 +
                                              ((((t * 4 + hi) ^ kx) & 7) << 3));
            const s16x8 vf1 = *(const s16x8*)(Vb + l31 * 72 +
                                              ((((t * 4 + 2 + hi) ^ kx) & 7) << 3));

#pragma unroll
            for (int qt = 0; qt < 2; ++qt) {
                f32x16 st = {};
                __builtin_amdgcn_s_setprio(1);
                st = __builtin_amdgcn_mfma_f32_32x32x16_bf16(
                    kfa, qf[qt][0], st, 0, 0, 0);
                st = __builtin_amdgcn_mfma_f32_32x32x16_bf16(
                    kfb, qf[qt][1], st, 0, 0, 0);
                __builtin_amdgcn_s_setprio(0);

                uint w[4], w2[4];
                float ls = 0.f;
#pragma unroll
                for (int g = 0; g < 4; ++g) {
                    const float p0 = __builtin_amdgcn_exp2f(st[4 * g + 0]);
                    const float p1 = __builtin_amdgcn_exp2f(st[4 * g + 1]);
                    const float p2 = __builtin_amdgcn_exp2f(st[4 * g + 2]);
                    const float p3 = __builtin_amdgcn_exp2f(st[4 * g + 3]);
                    ls += (p0 + p1) + (p2 + p3);
                    w[g]  = pk2(p0, p1);
                    w2[g] = pk2(p2, p3);
                }
                uint a0 = w[0],  c0 = w[1];  plswap(a0, c0);
                uint a1 = w2[0], c1 = w2[1]; plswap(a1, c1);
                const s16x8 pfA = __builtin_bit_cast(s16x8, (u32x4){a0, a1, c0, c1});
                uint b0 = w[2],  d0 = w[3];  plswap(b0, d0);
                uint b1 = w2[2], d1 = w2[3]; plswap(b1, d1);
                const s16x8 pfB = __builtin_bit_cast(s16x8, (u32x4){b0, b1, d0, d1});

                __builtin_amdgcn_s_setprio(1);
                if (qt == 0) {
                    laccA += ls;
                    oaccA = __builtin_amdgcn_mfma_f32_32x32x16_bf16(vf0, pfA, oaccA, 0, 0, 0);
                    oaccA = __builtin_amdgcn_mfma_f32_32x32x16_bf16(vf1, pfB, oaccA, 0, 0, 0);
                } else {
                    laccB += ls;
                    oaccB = __builtin_amdgcn_mfma_f32_32x32x16_bf16(vf0, pfA, oaccB, 0, 0, 0);
                    oaccB = __builtin_amdgcn_mfma_f32_32x32x16_bf16(vf1, pfB, oaccB, 0, 0, 0);
                }
                __builtin_amdgcn_s_setprio(0);
            }
        }

        __syncthreads();
    }

    // l reduce + write per q-tile
#pragma unroll
    for (int qt = 0; qt < 2; ++qt) {
        float lacc = qt ? laccB : laccA;
        {
            uint a = __builtin_bit_cast(uint, lacc), b = a;
            plswap(a, b);
            lacc = __builtin_bit_cast(float, a) + __builtin_bit_cast(float, b);
        }
        const f32x16& oacc = qt ? oaccB : oaccA;
        const int n = q0 + qt * 32 + l31;
        ushort* Ops = Opb + (size_t)s * (NPOS * NCH) + n * NCH + h * HD;
#pragma unroll
        for (int g = 0; g < 4; ++g) {
            *(u32x2*)(Ops + g * 8 + hi * 4) =
                (u32x2){pk2(oacc[4 * g + 0], oacc[4 * g + 1]),
                        pk2(oacc[4 * g + 2], oacc[4 * g + 3])};
        }
        if (lane < 32)
            Ml[(s * 8 + h) * NPOS + n] = lacc;
    }
}

// ------- fused split-K combine + output projection -------
template <int NS>
__global__ __launch_bounds__(256) void fused_out_kernel(
    const ushort* __restrict__ Opb, const float* __restrict__ Ml,
    const ushort* __restrict__ Wh, const ushort* __restrict__ Wl,
    const float* __restrict__ bias, float* __restrict__ Y)
{
    __shared__ __align__(16) ushort lds[8192];   // hi @0, lo @4096 (ushorts)
    const int tid = threadIdx.x;
    const int n0  = blockIdx.x * 16;

    // --- phase 1: combine -> LDS tiled hi/lo ---
    {
        const int nl = tid >> 4;              // 0..15
        const int c0 = (tid & 15) * 16;
        const int n  = n0 + nl;
        const int h  = c0 >> 5;
        float l = 0.f;
#pragma unroll
        for (int s = 0; s < NS; ++s)
            l += Ml[(s * 8 + h) * NPOS + n];
        const float inv = 1.f / l;

        float f[16];
#pragma unroll
        for (int i = 0; i < 16; ++i) f[i] = 0.f;
#pragma unroll
        for (int s = 0; s < NS; ++s) {
            const s16x8 r0 = load8(Opb + (size_t)s * (NPOS * NCH) + n * NCH + c0);
            const s16x8 r1 = load8(Opb + (size_t)s * (NPOS * NCH) + n * NCH + c0 + 8);
#pragma unroll
            for (int i = 0; i < 8; ++i) {
                f[i]     += bfval((ushort)r0[i]);
                f[i + 8] += bfval((ushort)r1[i]);
            }
        }
#pragma unroll
        for (int i = 0; i < 16; ++i) {
            const int c = c0 + i;
            const float v = f[i] * inv;
            const ushort hb = bfbits(v);
            const ushort lb = bfbits(v - bfval(hb));
            const int idx = ((c >> 5) * 64 + (((c >> 3) & 3) * 16) + nl) * 8 + (c & 7);
            lds[idx]        = hb;
            lds[4096 + idx] = lb;
        }
    }
    __syncthreads();

    // --- phase 2: C = Wp @ F + bias ---
    const int wid = tid >> 6, lane = tid & 63;
    const int lq = lane & 15, grp = lane >> 4;

    f32x4 acc[4];
#pragma unroll
    for (int ot = 0; ot < 4; ++ot) acc[ot] = (f32x4){0.f, 0.f, 0.f, 0.f};

#pragma unroll
    for (int kc = 0; kc < 8; ++kc) {
        const s16x8 bh = *(const s16x8*)(lds + (kc * 64 + lane) * 8);
        const s16x8 bl = *(const s16x8*)(lds + 4096 + (kc * 64 + lane) * 8);
#pragma unroll
        for (int ot = 0; ot < 4; ++ot) {
            const int To = wid * 4 + ot;
            const s16x8 ah = load8(Wh + ((To * 8 + kc) * 64 + lane) * 8);
            const s16x8 al = load8(Wl + ((To * 8 + kc) * 64 + lane) * 8);
            acc[ot] = __builtin_amdgcn_mfma_f32_16x16x32_bf16(ah, bh, acc[ot], 0, 0, 0);
            acc[ot] = __builtin_amdgcn_mfma_f32_16x16x32_bf16(ah, bl, acc[ot], 0, 0, 0);
            acc[ot] = __builtin_amdgcn_mfma_f32_16x16x32_bf16(al, bh, acc[ot], 0, 0, 0);
        }
    }

#pragma unroll
    for (int ot = 0; ot < 4; ++ot) {
        const int o0 = (wid * 4 + ot) * 16;
        const f32x4 b4 = *(const f32x4*)(bias + o0 + grp * 4);
#pragma unroll
        for (int r = 0; r < 4; ++r)
            Y[(o0 + grp * 4 + r) * NPOS + n0 + lq] = acc[ot][r] + b4[r];
    }
}

extern "C" void kernel_launch(void* const* d_in, const int* in_sizes, int n_in,
                              void* d_out, int out_size, void* d_ws, size_t ws_size,
                              hipStream_t stream) {
    const float* x1 = (const float*)d_in[0];
    const float* x2 = (const float*)d_in[1];
    const float* Wq = (const float*)d_in[2];
    const float* Wk = (const float*)d_in[3];
    const float* Wv = (const float*)d_in[4];
    const float* Wp = (const float*)d_in[5];
    const float* bp = (const float*)d_in[6];
    float* out = (float*)d_out;

    const size_t MB = 1u << 20;
    char* wsc = (char*)d_ws;
    const float qscale = (float)(0.17677669529663687 * 1.4426950408889634);

    if (ws_size >= 25 * MB) {
        // NSPLIT=8: Opb 16MB @0, qt@16, kt@18, vt@20, wsp@22, Ml@23.25
        ushort* Opb = (ushort*)(wsc + 0 * MB);
        ushort* qt  = (ushort*)(wsc + 16 * MB);
        ushort* kt  = (ushort*)(wsc + 18 * MB);
        ushort* vt  = (ushort*)(wsc + 20 * MB);
        ushort* wsp = (ushort*)(wsc + 22 * MB);
        float*  Ml  = (float*)(wsc + 23 * MB + 256 * 1024);

        convert_w_kernel<<<dim3(64, 4), 256, 0, stream>>>(
            Wq, Wk, Wv, Wp, wsp, qscale);
        fused_qkv_kernel<<<dim3(128, 2), 256, 0, stream>>>(
            x1, x2, wsp, qt, kt, vt);
        attn_mfma_kernel<8><<<1024, 256, 0, stream>>>(qt, kt, vt, Opb, Ml);
        fused_out_kernel<8><<<256, 256, 0, stream>>>(
            Opb, Ml, wsp + 393216, wsp + 458752, bp, out);
    } else {
        // NSPLIT=4: Opb 8MB @0, qt@8, kt@10, vt@12, wsp@14, Ml@15
        ushort* Opb = (ushort*)(wsc + 0 * MB);
        ushort* qt  = (ushort*)(wsc + 8 * MB);
        ushort* kt  = (ushort*)(wsc + 10 * MB);
        ushort* vt  = (ushort*)(wsc + 12 * MB);
        ushort* wsp = (ushort*)(wsc + 14 * MB);
        float*  Ml  = (float*)(wsc + 15 * MB);

        convert_w_kernel<<<dim3(64, 4), 256, 0, stream>>>(
            Wq, Wk, Wv, Wp, wsp, qscale);
        fused_qkv_kernel<<<dim3(128, 2), 256, 0, stream>>>(
            x1, x2, wsp, qt, kt, vt);
        attn_mfma_kernel<4><<<512, 256, 0, stream>>>(qt, kt, vt, Opb, Ml);
        fused_out_kernel<4><<<256, 256, 0, stream>>>(
            Opb, Ml, wsp + 393216, wsp + 458752, bp, out);
    }
}

// Round 19
// 75.568 us; speedup vs baseline: 1.0181x; 1.0141x over previous
//
#include <hip/hip_runtime.h>

#define NPOS 4096      // H*W
#define NCH  256       // channels
#define HD   32        // head dim
#define KB   128       // keys per attention step
#define NSPLIT 4
#define SPLIT_KEYS (NPOS / NSPLIT)
#define NSTEP (SPLIT_KEYS / KB)

// fragment-tiled layout: element (row o, col c) of a [R][256] bf16 matrix at
// ushort offset TOFF(o,c); a wave's (o-tile, kc) fragment = contiguous 1KB.
#define TOFF(o, c) (((((o) >> 4) * 8 + ((c) >> 5)) * 64 + \
                     ((((c) >> 3) & 3) * 16) + ((o) & 15)) * 8 + ((c) & 7))

typedef float f32x4  __attribute__((ext_vector_type(4)));
typedef float f32x16 __attribute__((ext_vector_type(16)));
typedef short s16x8  __attribute__((ext_vector_type(8)));
typedef uint  u32x2  __attribute__((ext_vector_type(2)));
typedef uint  u32x4  __attribute__((ext_vector_type(4)));
typedef int   i32x2  __attribute__((ext_vector_type(2)));

static __device__ __forceinline__ s16x8 load8(const ushort* p) {
    return *(const s16x8*)p;
}
static __device__ __forceinline__ ushort bfbits(float x) {
    __bf16 b = (__bf16)x;
    return __builtin_bit_cast(unsigned short, b);
}
static __device__ __forceinline__ float bfval(ushort u) {
    uint x = (uint)u << 16;
    return __builtin_bit_cast(float, x);
}
static __device__ __forceinline__ uint pk2(float a, float b) {
    return (uint)bfbits(a) | ((uint)bfbits(b) << 16);
}
// permlane32_swap: a -> (a_lo, b_lo-from-partner), b -> (a_hi, b_hi)
static __device__ __forceinline__ void plswap(uint& a, uint& b) {
    i32x2 r = __builtin_amdgcn_permlane32_swap((int)a, (int)b, false, false);
    a = (uint)r[0];
    b = (uint)r[1];
}

// ---------------- fused input conversion (tiled outputs) ----------------
// z=0: x1 -> xt1 hi/lo tiled; z=1: x2 -> xt2; z=2: W matrices -> wsp tiled.
__global__ __launch_bounds__(256) void convert_kernel(
    const float* __restrict__ x1, const float* __restrict__ x2,
    const float* __restrict__ Wq, const float* __restrict__ Wk,
    const float* __restrict__ Wv, const float* __restrict__ Wp,
    ushort* __restrict__ xt1h, ushort* __restrict__ xt1l,
    ushort* __restrict__ xt2h, ushort* __restrict__ xt2l,
    ushort* __restrict__ wsp, float qscale)
{
    if (blockIdx.z == 2) {
        const int m = blockIdx.y;
        const float* src = m == 0 ? Wq : m == 1 ? Wk : m == 2 ? Wv : Wp;
        const float sc = m == 0 ? qscale : 1.f;
        const int idx = (blockIdx.x * 256 + threadIdx.x) * 4;
        const int o = idx >> 8, c0 = idx & 255;
        f32x4 w = *(const f32x4*)(src + idx);
        w *= sc;
        ushort h[4], l[4];
#pragma unroll
        for (int i = 0; i < 4; ++i) {
            h[i] = bfbits(w[i]);
            l[i] = bfbits(w[i] - bfval(h[i]));
        }
        ushort* H = wsp + m * 2 * 65536;
        const int off = TOFF(o, c0);
        *(u32x2*)(H + off)         = (u32x2){(uint)h[0] | ((uint)h[1] << 16),
                                             (uint)h[2] | ((uint)h[3] << 16)};
        *(u32x2*)(H + 65536 + off) = (u32x2){(uint)l[0] | ((uint)l[1] << 16),
                                             (uint)l[2] | ((uint)l[3] << 16)};
        return;
    }
    __shared__ float tile[64][65];
    const float* X = blockIdx.z ? x2 : x1;
    ushort* Hd = blockIdx.z ? xt2h : xt1h;
    ushort* Ld = blockIdx.z ? xt2l : xt1l;
    const int n0 = blockIdx.x * 64, c0 = blockIdx.y * 64;
    const int tj = threadIdx.x & 63, ti = threadIdx.x >> 6;
#pragma unroll
    for (int r = 0; r < 16; ++r) {
        int i = r * 4 + ti;
        tile[i][tj] = X[(c0 + i) * NPOS + n0 + tj];
    }
    __syncthreads();
#pragma unroll
    for (int r = 0; r < 16; ++r) {
        int i = r * 4 + ti;                       // n offset
        float v = tile[tj][i];                    // X[c0+tj][n0+i]
        ushort h = bfbits(v);
        ushort l = bfbits(v - bfval(h));
        const int off = TOFF(n0 + i, c0 + tj);
        Hd[off] = h;
        Ld[off] = l;
    }
}

// ---------------- fused QKV projection (bf16x3 MFMA, tiled operands) ------
// grid (128, 12): y>>2 = m (0 Q from x1, 1 K from x2, 2 V from x2), y&3 = ob.
// All fragment loads are base + lane*8 (contiguous 1KB per wave).
__global__ __launch_bounds__(256) void gemm_qkv_kernel(
    const ushort* __restrict__ wsp,
    const ushort* __restrict__ x1h, const ushort* __restrict__ x1l,
    const ushort* __restrict__ x2h, const ushort* __restrict__ x2l,
    ushort* __restrict__ qt, ushort* __restrict__ kt, ushort* __restrict__ vt)
{
    const int m  = blockIdx.y >> 2;
    const int ob = blockIdx.y & 3;
    const ushort* Wh = wsp + m * 131072;
    const ushort* Wl = Wh + 65536;
    const ushort* Bh = (m == 0) ? x1h : x2h;
    const ushort* Bl = (m == 0) ? x1l : x2l;

    const int wid = threadIdx.x >> 6, lane = threadIdx.x & 63;
    const int lq = lane & 15, grp = lane >> 4;
    const int o0 = ob * 64 + wid * 16;
    const int n0 = blockIdx.x * 32;
    const int To = o0 >> 4;          // W row-tile
    const int Tn = n0 >> 4;          // X row-tile base

    f32x4 acc[2];
    acc[0] = (f32x4){0.f, 0.f, 0.f, 0.f};
    acc[1] = acc[0];
#pragma unroll
    for (int kc = 0; kc < 8; ++kc) {
        const s16x8 ah = load8(Wh + ((To * 8 + kc) * 64 + lane) * 8);
        const s16x8 al = load8(Wl + ((To * 8 + kc) * 64 + lane) * 8);
#pragma unroll
        for (int nt = 0; nt < 2; ++nt) {
            const s16x8 bh = load8(Bh + (((Tn + nt) * 8 + kc) * 64 + lane) * 8);
            const s16x8 bl = load8(Bl + (((Tn + nt) * 8 + kc) * 64 + lane) * 8);
            acc[nt] = __builtin_amdgcn_mfma_f32_16x16x32_bf16(ah, bh, acc[nt], 0, 0, 0);
            acc[nt] = __builtin_amdgcn_mfma_f32_16x16x32_bf16(ah, bl, acc[nt], 0, 0, 0);
            acc[nt] = __builtin_amdgcn_mfma_f32_16x16x32_bf16(al, bh, acc[nt], 0, 0, 0);
        }
    }
    if (m < 2) {
        ushort* Y = m ? kt : qt;
        const int head = o0 >> 5, d0 = (o0 & 31) + grp * 4;
#pragma unroll
        for (int nt = 0; nt < 2; ++nt) {
            const int n = n0 + nt * 16 + lq;
            *(u32x2*)(Y + head * (NPOS * HD) + n * HD + d0) =
                (u32x2){pk2(acc[nt][0], acc[nt][1]), pk2(acc[nt][2], acc[nt][3])};
        }
    } else {
#pragma unroll
        for (int nt = 0; nt < 2; ++nt) {
            const int n = n0 + nt * 16 + lq;
#pragma unroll
            for (int r = 0; r < 4; ++r)
                vt[(o0 + grp * 4 + r) * NPOS + n] = bfbits(acc[nt][r]);
        }
    }
}

// ---- MFMA flash attention: 32x32, no max, LDS dbuf (1 barrier/step) ----
// grid 1024: s = bid>>8, h = bid&7, qblk = (bid&255)>>3. KB=128, 8 steps.
__global__ __launch_bounds__(256) void attn_mfma_kernel(
    const ushort* __restrict__ Qt,   // [8][4096][32] bf16, pre-scaled s*log2e
    const ushort* __restrict__ Kt,   // [8][4096][32] bf16
    const ushort* __restrict__ Vt,   // [8][32][4096] bf16
    ushort* __restrict__ Opb,        // [4][4096][256] bf16 unnormalized
    float* __restrict__ Ml)          // [4][8][4096] f32 (l)
{
    __shared__ __align__(16) ushort lds[18944];  // K0@0 K1@5120 V0@10240 V1@14592
    const int bid  = blockIdx.x;
    const int s    = bid >> 8;
    const int h    = bid & 7;
    const int qblk = (bid & 255) >> 3;   // 0..31
    const int tid  = threadIdx.x;
    const int wid  = tid >> 6;
    const int lane = tid & 63;
    const int l31  = lane & 31;
    const int hi   = lane >> 5;
    const int q0   = qblk * 128 + wid * 32;
    const int k0   = s * SPLIT_KEYS;
    const int hq   = h * (NPOS * HD);

    s16x8 qf[2];
#pragma unroll
    for (int kh = 0; kh < 2; ++kh)
        qf[kh] = load8(Qt + hq + (q0 + l31) * HD + kh * 16 + hi * 8);

    const int kr0 = tid >> 2, kc0 = tid & 3;
    const ushort* kS = Kt + hq + kr0 * HD + kc0 * 8;
    const int kdst0 = kr0 * 40 + ((kc0 ^ ((kr0 >> 3) & 3)) & 3) * 8;
    const int kdst1 = kdst0 + 64 * 40;

    const int vr0 = tid >> 4, vc0 = tid & 15;
    const ushort* vS = Vt + h * (HD * NPOS) + vr0 * NPOS + vc0 * 8;
    const int vdst0 = vr0 * 136 + ((vc0 ^ ((vr0 >> 3) & 3)) & 15) * 8;
    const int vdst1 = (vr0 + 16) * 136 +
                      ((vc0 ^ (((vr0 + 16) >> 3) & 3)) & 15) * 8;

    const int kx = l31 >> 3;

    s16x8 onesf;
#pragma unroll
    for (int i = 0; i < 8; ++i) onesf[i] = (short)0x3F80;

    f32x16 oacc = {};
    f32x16 accl = {};

    // prologue: tile0 -> buf0; prefetch tile1 into regs
    *(s16x8*)(lds + kdst0)         = load8(kS + (size_t)k0 * HD);
    *(s16x8*)(lds + kdst1)         = load8(kS + (size_t)k0 * HD + 64 * HD);
    *(s16x8*)(lds + 10240 + vdst0) = load8(vS + k0);
    *(s16x8*)(lds + 10240 + vdst1) = load8(vS + k0 + 16 * NPOS);
    const int m1 = (NSTEP > 1) ? k0 + KB : k0;
    s16x8 kra = load8(kS + (size_t)m1 * HD);
    s16x8 krb = load8(kS + (size_t)m1 * HD + 64 * HD);
    s16x8 vra = load8(vS + m1);
    s16x8 vrb = load8(vS + m1 + 16 * NPOS);
    __syncthreads();

    for (int step = 0; step < NSTEP; ++step) {
        const int cur = step & 1;
        ushort* const Kb = lds + cur * 5120;
        ushort* const Vb = lds + 10240 + cur * 4352;

        // write prefetched tile (step+1) into the other buffer
        {
            ushort* const Kn = lds + (cur ^ 1) * 5120;
            ushort* const Vn = lds + 10240 + (cur ^ 1) * 4352;
            *(s16x8*)(Kn + kdst0) = kra;
            *(s16x8*)(Kn + kdst1) = krb;
            *(s16x8*)(Vn + vdst0) = vra;
            *(s16x8*)(Vn + vdst1) = vrb;
        }
        // issue loads for tile step+2
        const int mn = (step + 2 < NSTEP) ? k0 + (step + 2) * KB : k0;
        kra = load8(kS + (size_t)mn * HD);
        krb = load8(kS + (size_t)mn * HD + 64 * HD);
        vra = load8(vS + mn);
        vrb = load8(vS + mn + 16 * NPOS);

#pragma unroll
        for (int t = 0; t < 4; ++t) {
            const int krow = (t * 32 + l31) * 40;
            const s16x8 kfa = *(const s16x8*)(Kb + krow + ((hi ^ kx) & 3) * 8);
            const s16x8 kfb = *(const s16x8*)(Kb + krow + (((2 + hi) ^ kx) & 3) * 8);
            f32x16 st = {};
            __builtin_amdgcn_s_setprio(1);
            st = __builtin_amdgcn_mfma_f32_32x32x16_bf16(kfa, qf[0], st, 0, 0, 0);
            st = __builtin_amdgcn_mfma_f32_32x32x16_bf16(kfb, qf[1], st, 0, 0, 0);
            __builtin_amdgcn_s_setprio(0);

            const s16x8 vf0 = *(const s16x8*)(Vb + l31 * 136 +
                                              (((t * 4 + hi) ^ kx) & 15) * 8);
            const s16x8 vf1 = *(const s16x8*)(Vb + l31 * 136 +
                                              (((t * 4 + 2 + hi) ^ kx) & 15) * 8);

            uint w[4], w2[4];
#pragma unroll
            for (int g = 0; g < 4; ++g) {
                const float p0 = __builtin_amdgcn_exp2f(st[4 * g + 0]);
                const float p1 = __builtin_amdgcn_exp2f(st[4 * g + 1]);
                const float p2 = __builtin_amdgcn_exp2f(st[4 * g + 2]);
                const float p3 = __builtin_amdgcn_exp2f(st[4 * g + 3]);
                w[g]  = pk2(p0, p1);
                w2[g] = pk2(p2, p3);
            }
            uint a0 = w[0],  c0 = w[1];  plswap(a0, c0);
            uint a1 = w2[0], c1 = w2[1]; plswap(a1, c1);
            const s16x8 pfA = __builtin_bit_cast(s16x8, (u32x4){a0, a1, c0, c1});
            uint b0 = w[2],  d0 = w[3];  plswap(b0, d0);
            uint b1 = w2[2], d1 = w2[3]; plswap(b1, d1);
            const s16x8 pfB = __builtin_bit_cast(s16x8, (u32x4){b0, b1, d0, d1});

            __builtin_amdgcn_s_setprio(1);
            oacc = __builtin_amdgcn_mfma_f32_32x32x16_bf16(vf0, pfA, oacc, 0, 0, 0);
            oacc = __builtin_amdgcn_mfma_f32_32x32x16_bf16(vf1, pfB, oacc, 0, 0, 0);
            accl = __builtin_amdgcn_mfma_f32_32x32x16_bf16(onesf, pfA, accl, 0, 0, 0);
            accl = __builtin_amdgcn_mfma_f32_32x32x16_bf16(onesf, pfB, accl, 0, 0, 0);
            __builtin_amdgcn_s_setprio(0);
        }

        __syncthreads();
    }

    // --- write unnormalized partials (bf16, n-major) + l ---
    const int n = q0 + l31;
    ushort* Ops = Opb + (size_t)s * (NPOS * NCH) + n * NCH + h * HD;
#pragma unroll
    for (int g = 0; g < 4; ++g) {
        *(u32x2*)(Ops + g * 8 + hi * 4) =
            (u32x2){pk2(oacc[4 * g + 0], oacc[4 * g + 1]),
                    pk2(oacc[4 * g + 2], oacc[4 * g + 3])};
    }
    if (lane < 32)
        Ml[(s * 8 + h) * NPOS + n] = accl[0];
}

// split-K combine: Opb[4][n][c] bf16 -> FT hi/lo bf16, TILED layout out.
__global__ __launch_bounds__(256) void combine_kernel(
    const ushort* __restrict__ Opb, const float* __restrict__ Ml,
    ushort* __restrict__ FH, ushort* __restrict__ FL)
{
    const int n = blockIdx.x * 4 + (threadIdx.x >> 6);
    const int c = (threadIdx.x & 63) * 4;
    const int h = c >> 5;
    float l = 0.f;
#pragma unroll
    for (int s = 0; s < NSPLIT; ++s)
        l += Ml[(s * 8 + h) * NPOS + n];
    const float inv = 1.f / l;

    float sum[4] = {0.f, 0.f, 0.f, 0.f};
#pragma unroll
    for (int s = 0; s < NSPLIT; ++s) {
        const u32x2 raw = *(const u32x2*)(Opb + (size_t)s * (NPOS * NCH) +
                                          n * NCH + c);
        sum[0] += bfval((ushort)(raw[0] & 0xFFFF));
        sum[1] += bfval((ushort)(raw[0] >> 16));
        sum[2] += bfval((ushort)(raw[1] & 0xFFFF));
        sum[3] += bfval((ushort)(raw[1] >> 16));
    }
    ushort hb[4], lb[4];
#pragma unroll
    for (int i = 0; i < 4; ++i) {
        float f = sum[i] * inv;
        hb[i] = bfbits(f);
        lb[i] = bfbits(f - bfval(hb[i]));
    }
    const int off = TOFF(n, c);
    *(u32x2*)(FH + off) = (u32x2){(uint)hb[0] | ((uint)hb[1] << 16),
                                  (uint)hb[2] | ((uint)hb[3] << 16)};
    *(u32x2*)(FL + off) = (u32x2){(uint)lb[0] | ((uint)lb[1] << 16),
                                  (uint)lb[2] | ((uint)lb[3] << 16)};
}

// Output projection: C = Wp @ F + bias, f32 out [256][4096]. Tiled operands.
__global__ __launch_bounds__(256) void gemm_out_kernel(
    const ushort* __restrict__ Wh, const ushort* __restrict__ Wl,
    const ushort* __restrict__ Bh, const ushort* __restrict__ Bl,
    const float* __restrict__ bias, float* __restrict__ Y)
{
    const int wid = threadIdx.x >> 6, lane = threadIdx.x & 63;
    const int lq = lane & 15, grp = lane >> 4;
    const int o0 = blockIdx.y * 64 + wid * 16;
    const int n0 = blockIdx.x * 32;
    const int To = o0 >> 4;
    const int Tn = n0 >> 4;

    f32x4 acc[2];
    acc[0] = (f32x4){0.f, 0.f, 0.f, 0.f};
    acc[1] = acc[0];
#pragma unroll
    for (int kc = 0; kc < 8; ++kc) {
        const s16x8 ah = load8(Wh + ((To * 8 + kc) * 64 + lane) * 8);
        const s16x8 al = load8(Wl + ((To * 8 + kc) * 64 + lane) * 8);
#pragma unroll
        for (int nt = 0; nt < 2; ++nt) {
            const s16x8 bh = load8(Bh + (((Tn + nt) * 8 + kc) * 64 + lane) * 8);
            const s16x8 bl = load8(Bl + (((Tn + nt) * 8 + kc) * 64 + lane) * 8);
            acc[nt] = __builtin_amdgcn_mfma_f32_16x16x32_bf16(ah, bh, acc[nt], 0, 0, 0);
            acc[nt] = __builtin_amdgcn_mfma_f32_16x16x32_bf16(ah, bl, acc[nt], 0, 0, 0);
            acc[nt] = __builtin_amdgcn_mfma_f32_16x16x32_bf16(al, bh, acc[nt], 0, 0, 0);
        }
    }
    const f32x4 b4 = *(const f32x4*)(bias + o0 + grp * 4);
#pragma unroll
    for (int nt = 0; nt < 2; ++nt) {
        const int n = n0 + nt * 16 + lq;
#pragma unroll
        for (int r = 0; r < 4; ++r)
            Y[(o0 + grp * 4 + r) * NPOS + n] = acc[nt][r] + b4[r];
    }
}

extern "C" void kernel_launch(void* const* d_in, const int* in_sizes, int n_in,
                              void* d_out, int out_size, void* d_ws, size_t ws_size,
                              hipStream_t stream) {
    const float* x1 = (const float*)d_in[0];
    const float* x2 = (const float*)d_in[1];
    const float* Wq = (const float*)d_in[2];
    const float* Wk = (const float*)d_in[3];
    const float* Wv = (const float*)d_in[4];
    const float* Wp = (const float*)d_in[5];
    const float* bp = (const float*)d_in[6];
    float* out = (float*)d_out;

    const size_t MB = 1u << 20;
    char* wsc = (char*)d_ws;
    ushort* xt1h = (ushort*)(wsc + 0 * MB);
    ushort* xt1l = (ushort*)(wsc + 2 * MB);
    ushort* xt2h = (ushort*)(wsc + 4 * MB);
    ushort* xt2l = (ushort*)(wsc + 6 * MB);
    ushort* qt   = (ushort*)(wsc + 8 * MB);
    ushort* kt   = (ushort*)(wsc + 10 * MB);
    ushort* vt   = (ushort*)(wsc + 12 * MB);
    ushort* wsp  = (ushort*)(wsc + 14 * MB);   // [4][2][65536] bf16 tiled
    float*  Ml   = (float*)(wsc + 15 * MB);    // [4][8][4096] f32 (l)
    ushort* Opb  = (ushort*)(wsc + 0 * MB);    // [4][4096][256] bf16 (over xt*)
    ushort* fth  = (ushort*)(wsc + 8 * MB);    // over qt (tiled)
    ushort* ftl  = (ushort*)(wsc + 10 * MB);   // over kt (tiled)

    const float qscale = (float)(0.17677669529663687 * 1.4426950408889634);

    convert_kernel<<<dim3(64, 4, 3), 256, 0, stream>>>(
        x1, x2, Wq, Wk, Wv, Wp, xt1h, xt1l, xt2h, xt2l, wsp, qscale);

    gemm_qkv_kernel<<<dim3(128, 12), 256, 0, stream>>>(
        wsp, xt1h, xt1l, xt2h, xt2l, qt, kt, vt);

    attn_mfma_kernel<<<1024, 256, 0, stream>>>(qt, kt, vt, Opb, Ml);

    combine_kernel<<<1024, 256, 0, stream>>>(Opb, Ml, fth, ftl);

    ushort* wph = wsp + 393216;
    ushort* wpl = wsp + 458752;
    gemm_out_kernel<<<dim3(128, 4), 256, 0, stream>>>(
        wph, wpl, fth, ftl, bp, out);
}